// Round 1
// baseline (133.838 us; speedup 1.0000x reference)
//
#include <hip/hip_runtime.h>

// out[n, d*W + w] = x[n + w - H, d] if the source token is inside the same
// variable-length sequence as token n, else 0.
// W=5, H=2, D=1024, 8 sequences.

#define WIN 5
#define HALF 2
#define DIM 1024
#define DV (DIM / 4)   // 256 float4 per x row
#define NSEQ 8

__global__ __launch_bounds__(DV) void inflate_kernel(
    const float4* __restrict__ x4,    // [N][DV]
    const int*    __restrict__ lengths, // [NSEQ]
    float4*       __restrict__ out4,  // [N][DV*WIN]
    int N)
{
    const int n = blockIdx.x;          // token index
    const int g = threadIdx.x;         // 4-column group, 0..255

    // Find owning sequence (uniform across block; 8-step scalar loop).
    int start = 0, len = 0, acc = 0;
#pragma unroll
    for (int s = 0; s < NSEQ; ++s) {
        int L = lengths[s];
        if (n >= acc && n < acc + L) { start = acc; len = L; }
        acc += L;
    }
    const int local = n - start;

    // Load the 5 source rows (4 floats each) into registers, zero-fill OOB.
    float vr[WIN][4];
#pragma unroll
    for (int r = 0; r < WIN; ++r) {
        const int sl = local + r - HALF;
        if (sl >= 0 && sl < len) {
            float4 t = x4[(size_t)(start + sl) * DV + g];
            vr[r][0] = t.x; vr[r][1] = t.y; vr[r][2] = t.z; vr[r][3] = t.w;
        } else {
            vr[r][0] = 0.f; vr[r][1] = 0.f; vr[r][2] = 0.f; vr[r][3] = 0.f;
        }
    }

    // 20 output floats for this thread start at out[n, (g*4)*WIN]:
    // p-th float (p=0..19) is (d0 + p/5, w = p%5) -> vr[p%5][p/5].
    float4* dst = out4 + (size_t)n * (DV * WIN) + (size_t)g * WIN;
#pragma unroll
    for (int k = 0; k < WIN; ++k) {
        float4 o;
        o.x = vr[(4*k + 0) % WIN][(4*k + 0) / WIN];
        o.y = vr[(4*k + 1) % WIN][(4*k + 1) / WIN];
        o.z = vr[(4*k + 2) % WIN][(4*k + 2) / WIN];
        o.w = vr[(4*k + 3) % WIN][(4*k + 3) / WIN];
        dst[k] = o;
    }
}

extern "C" void kernel_launch(void* const* d_in, const int* in_sizes, int n_in,
                              void* d_out, int out_size, void* d_ws, size_t ws_size,
                              hipStream_t stream) {
    const float* x       = (const float*)d_in[0];
    const int*   lengths = (const int*)d_in[1];
    float*       out     = (float*)d_out;

    const int N = in_sizes[0] / DIM;   // 16384

    dim3 grid(N), block(DV);
    hipLaunchKernelGGL(inflate_kernel, grid, block, 0, stream,
                       (const float4*)x, lengths, (float4*)out, N);
}

// Round 2
// 103.188 us; speedup vs baseline: 1.2970x; 1.2970x over previous
//
#include <hip/hip_runtime.h>

// out[n, d*W + w] = x[n + w - H, d] if source token is inside the same
// variable-length sequence as token n, else 0.  W=5, H=2, D=1024, 8 seqs.
//
// Block = one token, 256 threads.
// Phase 1: stage 5 rows (zero-filled when OOB) into LDS, coalesced float4.
// Phase 2: write 1280 float4 of output with block-stride mapping so every
//          store instruction is 64 lanes x 16B fully contiguous; the d*W+w
//          transpose is resolved by 4 scalar LDS reads per output float4.

#define WIN 5
#define HALF 2
#define DIM 1024
#define DV (DIM / 4)        // 256 float4 per x row
#define OUTV (DV * WIN)     // 1280 float4 per out row
#define NSEQ 8

__global__ __launch_bounds__(256) void inflate_kernel(
    const float4* __restrict__ x4,      // [N][DV]
    const int*    __restrict__ lengths, // [NSEQ]
    float4*       __restrict__ out4,    // [N][OUTV]
    int N)
{
    __shared__ float lds[WIN * DIM];    // lds[w*1024 + d]

    const int n = blockIdx.x;
    const int g = threadIdx.x;          // 0..255

    // Owning sequence (uniform across block).
    int start = 0, len = 0, acc = 0;
#pragma unroll
    for (int s = 0; s < NSEQ; ++s) {
        int L = lengths[s];
        if (n >= acc && n < acc + L) { start = acc; len = L; }
        acc += L;
    }
    const int local = n - start;

    // Phase 1: stage rows local-2 .. local+2 into LDS (zeros when OOB).
    float4* lds4 = (float4*)lds;
#pragma unroll
    for (int r = 0; r < WIN; ++r) {
        const int sl = local + r - HALF;
        float4 t;
        if (sl >= 0 && sl < len) {
            t = x4[(size_t)(start + sl) * DV + g];
        } else {
            t.x = 0.f; t.y = 0.f; t.z = 0.f; t.w = 0.f;
        }
        lds4[r * DV + g] = t;
    }
    __syncthreads();

    // Phase 2: out float4 j = k*256+g holds floats p=4j..4j+3,
    // p = d*5 + w  ->  value lds[w*1024 + d].
    float4* dst = out4 + (size_t)n * OUTV;
#pragma unroll
    for (int k = 0; k < WIN; ++k) {
        const int j  = k * 256 + g;
        const int p0 = 4 * j;
        float4 o;
        {
            int p = p0 + 0, d = p / WIN, w = p - d * WIN;
            o.x = lds[w * DIM + d];
        }
        {
            int p = p0 + 1, d = p / WIN, w = p - d * WIN;
            o.y = lds[w * DIM + d];
        }
        {
            int p = p0 + 2, d = p / WIN, w = p - d * WIN;
            o.z = lds[w * DIM + d];
        }
        {
            int p = p0 + 3, d = p / WIN, w = p - d * WIN;
            o.w = lds[w * DIM + d];
        }
        dst[j] = o;
    }
}

extern "C" void kernel_launch(void* const* d_in, const int* in_sizes, int n_in,
                              void* d_out, int out_size, void* d_ws, size_t ws_size,
                              hipStream_t stream) {
    const float* x       = (const float*)d_in[0];
    const int*   lengths = (const int*)d_in[1];
    float*       out     = (float*)d_out;

    const int N = in_sizes[0] / DIM;    // 16384

    dim3 grid(N), block(256);
    hipLaunchKernelGGL(inflate_kernel, grid, block, 0, stream,
                       (const float4*)x, lengths, (float4*)out, N);
}

// Round 4
// 72.086 us; speedup vs baseline: 1.8567x; 1.4315x over previous
//
#include <hip/hip_runtime.h>

// out[n, d*W + w] = x[n + w - H, d] if source token in same sequence, else 0.
// W=5, H=2, D=1024, 8 sequences, N=16384.
//
// Block = 8 consecutive tokens (256 threads). Stage 12 x-rows (tokens-2..+9,
// zero-clamped at [0,N)) into LDS, then each wave emits 2 full output rows
// with fully-coalesced nontemporal float4 stores; the d*W+w transpose is
// resolved by scalar LDS reads. Sequence-boundary masking only on the
// wave-uniform slow path. XCD-chunked blockIdx swizzle keeps the 5-row
// overlap between neighboring blocks inside one XCD's L2.

#define WIN 5
#define HALF 2
#define DIM 1024
#define DV (DIM / 4)        // 256 float4 per x row
#define OUTV (DV * WIN)     // 1280 float4 per out row
#define NSEQ 8
#define T 8                 // tokens per block
#define ROWS (T + 2 * HALF) // 12 staged rows

typedef float f32x4 __attribute__((ext_vector_type(4)));

__global__ __launch_bounds__(256) void inflate_kernel(
    const f32x4* __restrict__ x4,       // [N][DV]
    const int*   __restrict__ lengths,  // [NSEQ]
    f32x4*       __restrict__ out4,     // [N][OUTV]
    int N)
{
    __shared__ float lds[ROWS * DIM];   // 48 KB

    // Bijective XCD-chunked swizzle (gridDim.x = 2048, divisible by 8).
    const int nb    = gridDim.x;
    const int chunk = nb >> 3;
    const int bid   = blockIdx.x;
    const int newb  = (bid & 7) * chunk + (bid >> 3);
    const int t0    = newb * T;

    const int g = threadIdx.x;

    // Phase 1: stage rows t0-2 .. t0+9 (zero outside [0,N)).
    f32x4* lds4 = (f32x4*)lds;
#pragma unroll
    for (int rr = 0; rr < ROWS; ++rr) {
        const int gr = t0 - HALF + rr;
        f32x4 v = (f32x4)0.f;
        if (gr >= 0 && gr < N) v = x4[(size_t)gr * DV + g];
        lds4[rr * DV + g] = v;
    }

    // Hoist lengths into registers (uniform).
    int Ls[NSEQ];
#pragma unroll
    for (int s = 0; s < NSEQ; ++s) Ls[s] = lengths[s];

    __syncthreads();

    // Phase 2: wave wid emits tokens t0 + 2*wid + {0,1}.
    const int wid  = g >> 6;
    const int lane = g & 63;

#pragma unroll
    for (int ti = 0; ti < 2; ++ti) {
        const int tt = wid * 2 + ti;      // 0..7, wave-uniform
        const int n  = t0 + tt;

        // Owning sequence (wave-uniform).
        int start = 0, end = N, acc = 0;
#pragma unroll
        for (int s = 0; s < NSEQ; ++s) {
            const int L = Ls[s];
            if (n >= acc && n < acc + L) { start = acc; end = acc + L; }
            acc += L;
        }
        int wlo = start - n + HALF; if (wlo < 0) wlo = 0;
        int whi = end - n + HALF - 1; if (whi > WIN - 1) whi = WIN - 1;

        const float* ldsbase = lds + tt * DIM;   // + w*DIM + d
        f32x4* dst = out4 + (size_t)n * OUTV;

        if (wlo == 0 && whi == WIN - 1) {
#pragma unroll
            for (int k = 0; k < OUTV / 64; ++k) {   // 20 iters
                const unsigned j  = k * 64 + lane;
                const unsigned p0 = 4 * j;
                f32x4 o;
                { unsigned p = p0 + 0, d = p / WIN, w = p - d * WIN; o.x = ldsbase[w * DIM + d]; }
                { unsigned p = p0 + 1, d = p / WIN, w = p - d * WIN; o.y = ldsbase[w * DIM + d]; }
                { unsigned p = p0 + 2, d = p / WIN, w = p - d * WIN; o.z = ldsbase[w * DIM + d]; }
                { unsigned p = p0 + 3, d = p / WIN, w = p - d * WIN; o.w = ldsbase[w * DIM + d]; }
                __builtin_nontemporal_store(o, &dst[j]);
            }
        } else {
#pragma unroll
            for (int k = 0; k < OUTV / 64; ++k) {
                const unsigned j  = k * 64 + lane;
                const unsigned p0 = 4 * j;
                f32x4 o;
                { unsigned p = p0 + 0, d = p / WIN; int w = (int)(p - d * WIN);
                  o.x = (w >= wlo && w <= whi) ? ldsbase[w * DIM + d] : 0.f; }
                { unsigned p = p0 + 1, d = p / WIN; int w = (int)(p - d * WIN);
                  o.y = (w >= wlo && w <= whi) ? ldsbase[w * DIM + d] : 0.f; }
                { unsigned p = p0 + 2, d = p / WIN; int w = (int)(p - d * WIN);
                  o.z = (w >= wlo && w <= whi) ? ldsbase[w * DIM + d] : 0.f; }
                { unsigned p = p0 + 3, d = p / WIN; int w = (int)(p - d * WIN);
                  o.w = (w >= wlo && w <= whi) ? ldsbase[w * DIM + d] : 0.f; }
                __builtin_nontemporal_store(o, &dst[j]);
            }
        }
    }
}

extern "C" void kernel_launch(void* const* d_in, const int* in_sizes, int n_in,
                              void* d_out, int out_size, void* d_ws, size_t ws_size,
                              hipStream_t stream) {
    const float* x       = (const float*)d_in[0];
    const int*   lengths = (const int*)d_in[1];
    float*       out     = (float*)d_out;

    const int N = in_sizes[0] / DIM;    // 16384

    dim3 grid(N / T), block(256);
    hipLaunchKernelGGL(inflate_kernel, grid, block, 0, stream,
                       (const f32x4*)x, lengths, (f32x4*)out, N);
}